// Round 11
// baseline (2012.531 us; speedup 1.0000x reference)
//
#include <hip/hip_runtime.h>
#include <math.h>

#define N_NODES   50000
#define N_EDGES   800000
#define IN_FEAT   64
#define HIDDEN    32
#define GRID_SZ   4
#define N_GRAPHS  128
#define NEG_SLOPE 0.01f
#define SCAN_BLOCKS 196   // ceil(50000/256)

// ---------------------------------------------------------------------------
__global__ __launch_bounds__(256) void zero_int_kernel(int* __restrict__ p, int n) {
  const int i = blockIdx.x * 256 + threadIdx.x;
  if (i < n) p[i] = 0;
}
__global__ __launch_bounds__(256) void zero_kernel(float* __restrict__ p, int n) {
  const int i = blockIdx.x * 256 + threadIdx.x;
  if (i < n) p[i] = 0.f;
}

// ---------------------------------------------------------------------------
// CSR build: histogram of dst into deg[]
// ---------------------------------------------------------------------------
__global__ __launch_bounds__(256) void hist_kernel(
    const int* __restrict__ dst, int* __restrict__ deg) {
  const int e = blockIdx.x * 256 + threadIdx.x;
  if (e < N_EDGES) atomicAdd(&deg[dst[e]], 1);
}

// multi-block scan, step A: per-block sums of deg -> bsum[SCAN_BLOCKS]
__global__ __launch_bounds__(256) void scanA_kernel(
    const int* __restrict__ deg, int* __restrict__ bsum) {
  const int i = blockIdx.x * 256 + threadIdx.x;
  int v = (i < N_NODES) ? deg[i] : 0;
#pragma unroll
  for (int o = 32; o > 0; o >>= 1) v += __shfl_down(v, o, 64);
  __shared__ int ws[4];
  if ((threadIdx.x & 63) == 0) ws[threadIdx.x >> 6] = v;
  __syncthreads();
  if (threadIdx.x == 0) bsum[blockIdx.x] = ws[0] + ws[1] + ws[2] + ws[3];
}

// step B: single small block scans the 196 block sums -> exclusive offsets
__global__ __launch_bounds__(256) void scanB_kernel(
    int* __restrict__ bsum, int* __restrict__ row_ptr) {
  __shared__ int sh[256];
  const int t = threadIdx.x;
  int v = (t < SCAN_BLOCKS) ? bsum[t] : 0;
  sh[t] = v;
  __syncthreads();
  for (int o = 1; o < 256; o <<= 1) {
    const int u = (t >= o) ? sh[t - o] : 0;
    __syncthreads();
    sh[t] += u;
    __syncthreads();
  }
  bsum[t] = (t == 0) ? 0 : sh[t - 1];   // exclusive
  if (t == 0) row_ptr[N_NODES] = N_EDGES;
}

// step C: per-block exclusive scan + block offset -> row_ptr, cursor
__global__ __launch_bounds__(256) void scanC_kernel(
    const int* __restrict__ deg, const int* __restrict__ bsum,
    int* __restrict__ row_ptr, int* __restrict__ cursor) {
  __shared__ int sh[256];
  const int t = threadIdx.x;
  const int i = blockIdx.x * 256 + t;
  const int v = (i < N_NODES) ? deg[i] : 0;
  sh[t] = v;
  __syncthreads();
  for (int o = 1; o < 256; o <<= 1) {
    const int u = (t >= o) ? sh[t - o] : 0;
    __syncthreads();
    sh[t] += u;
    __syncthreads();
  }
  if (i < N_NODES) {
    const int excl = bsum[blockIdx.x] + sh[t] - v;
    row_ptr[i] = excl;
    cursor[i] = excl;
  }
}

// fill: adj[pos] = src, pos = cursor[dst]++
__global__ __launch_bounds__(256) void fill_kernel(
    const int* __restrict__ src, const int* __restrict__ dst,
    int* __restrict__ cursor, int* __restrict__ adj) {
  const int e = blockIdx.x * 256 + threadIdx.x;
  if (e < N_EDGES) {
    const int pos = atomicAdd(&cursor[dst[e]], 1);
    adj[pos] = src[e];
  }
}

// ---------------------------------------------------------------------------
// gather + fused update, float4: 8 lanes/node, each lane owns 4 feats.
// H[n] = leaky(H[n] + sum_{k in row(n)} T[adj[k]])
// ---------------------------------------------------------------------------
__global__ __launch_bounds__(256) void gather_update_v2(
    const float* __restrict__ T, const int* __restrict__ row_ptr,
    const int* __restrict__ adj, float* __restrict__ H) {
  const int gid = blockIdx.x * 256 + threadIdx.x;
  const int n = gid >> 3;
  const int q = gid & 7;          // float4 slot within the 32-float row
  if (n >= N_NODES) return;
  const int lo = row_ptr[n], hi = row_ptr[n + 1];
  const float4* __restrict__ T4 = reinterpret_cast<const float4*>(T);
  float4 acc = make_float4(0.f, 0.f, 0.f, 0.f);
  for (int k = lo; k < hi; ++k) {
    const int s = adj[k];
    const float4 t = T4[s * 8 + q];
    acc.x += t.x; acc.y += t.y; acc.z += t.z; acc.w += t.w;
  }
  float4* __restrict__ H4 = reinterpret_cast<float4*>(H);
  float4 h = H4[n * 8 + q];
  h.x += acc.x; h.y += acc.y; h.z += acc.z; h.w += acc.w;
  h.x = (h.x >= 0.f) ? h.x : NEG_SLOPE * h.x;
  h.y = (h.y >= 0.f) ? h.y : NEG_SLOPE * h.y;
  h.z = (h.z >= 0.f) ? h.z : NEG_SLOPE * h.z;
  h.w = (h.w >= 0.f) ? h.w : NEG_SLOPE * h.w;
  H4[n * 8 + q] = h;
}

// ---------------------------------------------------------------------------
// Input KAN v8: wave = o-octet, lanes = 64 nodes, zero LDS.
// Weights via VECTOR global loads (opaque-VGPR base defeats scalarization):
// L1-broadcast + deep vmcnt queue hides latency, unlike v7's s_load chain.
// 16 base pointers hoisted; i-loop uses immediate offsets (i*16B <= 1KB).
// ---------------------------------------------------------------------------
__global__ __launch_bounds__(256, 3) void kan_input_v8(
    const float* __restrict__ X, const float* __restrict__ W,
    float* __restrict__ H) {
  const int lane = threadIdx.x & 63;
  const int octet = threadIdx.x >> 6;   // 0..3
  const int node = blockIdx.x * 64 + lane;
  const int ns = (node < N_NODES) ? node : (N_NODES - 1);
  const float* __restrict__ xr = X + ns * IN_FEAT;

  int zero = 0;
  asm volatile("v_mov_b32 %0, %1" : "=v"(zero) : "v"(zero));  // opaque 0
  const float* __restrict__ wb = W + octet * 8 * (IN_FEAT * GRID_SZ) + zero;

  const float* wa[8];
  const float* wc[8];
#pragma unroll
  for (int oo = 0; oo < 8; ++oo) {
    wa[oo] = wb + oo * (IN_FEAT * GRID_SZ);
    wc[oo] = wb + HIDDEN * IN_FEAT * GRID_SZ + oo * (IN_FEAT * GRID_SZ);
  }

  float acc[8];
#pragma unroll
  for (int oo = 0; oo < 8; ++oo) acc[oo] = 0.f;

  for (int ch = 0; ch < 4; ++ch) {          // 4 chunks of 16 i
    float4 xv[4];
#pragma unroll
    for (int q = 0; q < 4; ++q)
      xv[q] = reinterpret_cast<const float4*>(xr)[ch * 4 + q];
#pragma unroll
    for (int il = 0; il < 16; ++il) {
      const float v = (il & 3) == 0 ? xv[il >> 2].x :
                      (il & 3) == 1 ? xv[il >> 2].y :
                      (il & 3) == 2 ? xv[il >> 2].z : xv[il >> 2].w;
      const int i = ch * 16 + il;
      float s1, c1;
      sincosf(v, &s1, &c1);
      const float c2 = c1*c1 - s1*s1, s2 = s1*c1 + c1*s1;
      const float c3 = c2*c1 - s2*s1, s3 = s2*c1 + c2*s1;
      const float c4 = c3*c1 - s3*s1, s4 = s3*c1 + c3*s1;
#pragma unroll
      for (int oo = 0; oo < 8; ++oo) {
        const float4 a = *reinterpret_cast<const float4*>(wa[oo] + i * 4);
        const float4 b = *reinterpret_cast<const float4*>(wc[oo] + i * 4);
        acc[oo] += c1*a.x + c2*a.y + c3*a.z + c4*a.w
                 + s1*b.x + s2*b.y + s3*b.z + s4*b.w;
      }
    }
  }
  if (node < N_NODES) {
    float* __restrict__ hr = H + node * HIDDEN + octet * 8;
    *reinterpret_cast<float4*>(hr)     = make_float4(acc[0], acc[1], acc[2], acc[3]);
    *reinterpret_cast<float4*>(hr + 4) = make_float4(acc[4], acc[5], acc[6], acc[7]);
  }
}

// ---------------------------------------------------------------------------
// Conv KAN v8: same vector-load structure, 32 input feats.
// ---------------------------------------------------------------------------
__global__ __launch_bounds__(256, 3) void kan_node_v8(
    const float* __restrict__ Hin, const float* __restrict__ W,
    float* __restrict__ T) {
  const int lane = threadIdx.x & 63;
  const int octet = threadIdx.x >> 6;
  const int node = blockIdx.x * 64 + lane;
  const int ns = (node < N_NODES) ? node : (N_NODES - 1);

  int zero = 0;
  asm volatile("v_mov_b32 %0, %1" : "=v"(zero) : "v"(zero));  // opaque 0
  const float* __restrict__ wb = W + octet * 8 * (HIDDEN * GRID_SZ) + zero;

  const float* wa[8];
  const float* wc[8];
#pragma unroll
  for (int oo = 0; oo < 8; ++oo) {
    wa[oo] = wb + oo * (HIDDEN * GRID_SZ);
    wc[oo] = wb + HIDDEN * HIDDEN * GRID_SZ + oo * (HIDDEN * GRID_SZ);
  }

  // preload own H row (32 floats)
  float hv[HIDDEN];
  const float4* __restrict__ hr4 = reinterpret_cast<const float4*>(Hin + ns * HIDDEN);
#pragma unroll
  for (int q = 0; q < HIDDEN / 4; ++q) {
    const float4 h4 = hr4[q];
    hv[q*4+0] = h4.x; hv[q*4+1] = h4.y; hv[q*4+2] = h4.z; hv[q*4+3] = h4.w;
  }

  float acc[8];
#pragma unroll
  for (int oo = 0; oo < 8; ++oo) acc[oo] = 0.f;

  for (int i = 0; i < HIDDEN; ++i) {
    const float v = hv[i];
    float s1, c1;
    sincosf(v, &s1, &c1);
    const float c2 = c1*c1 - s1*s1, s2 = s1*c1 + c1*s1;
    const float c3 = c2*c1 - s2*s1, s3 = s2*c1 + c2*s1;
    const float c4 = c3*c1 - s3*s1, s4 = s3*c1 + c3*s1;
#pragma unroll
    for (int oo = 0; oo < 8; ++oo) {
      const float4 a = *reinterpret_cast<const float4*>(wa[oo] + i * 4);
      const float4 b = *reinterpret_cast<const float4*>(wc[oo] + i * 4);
      acc[oo] += c1*a.x + c2*a.y + c3*a.z + c4*a.w
               + s1*b.x + s2*b.y + s3*b.z + s4*b.w;
    }
  }
  if (node < N_NODES) {
    float* __restrict__ tr = T + node * HIDDEN + octet * 8;
    *reinterpret_cast<float4*>(tr)     = make_float4(acc[0], acc[1], acc[2], acc[3]);
    *reinterpret_cast<float4*>(tr + 4) = make_float4(acc[4], acc[5], acc[6], acc[7]);
  }
}

// ---------------------------------------------------------------------------
// pool via run-length over sorted batch: thread = (range r, feat f)
// ---------------------------------------------------------------------------
#define POOL_RANGES 512
__global__ __launch_bounds__(256) void pool_rl(
    const float* __restrict__ H, const int* __restrict__ batch,
    float* __restrict__ sums, float* __restrict__ cnt) {
  const int tid = threadIdx.x;
  const int f = tid & 31;
  const int r = blockIdx.x * 8 + (tid >> 5);
  const int PER = (N_NODES + POOL_RANGES - 1) / POOL_RANGES;  // 98
  int n = r * PER;
  const int end = (n + PER < N_NODES) ? n + PER : N_NODES;
  if (n >= end) return;
  int g = batch[n];
  float acc = 0.f, c = 0.f;
  for (; n < end; ++n) {
    const int gn = batch[n];
    if (gn != g) {
      atomicAdd(&sums[g * HIDDEN + f], acc);
      if (f == 0) atomicAdd(&cnt[g], c);
      g = gn; acc = 0.f; c = 0.f;
    }
    acc += H[n * HIDDEN + f];
    c += 1.f;
  }
  atomicAdd(&sums[g * HIDDEN + f], acc);
  if (f == 0) atomicAdd(&cnt[g], c);
}

// ---------------------------------------------------------------------------
__global__ __launch_bounds__(128) void readout_kernel(
    const float* __restrict__ sums, const float* __restrict__ cnt,
    const float* __restrict__ Wout, const float* __restrict__ bout,
    float* __restrict__ out) {
  const int g = threadIdx.x;
  if (g < N_GRAPHS) {
    const float c = fmaxf(cnt[g], 1.0f);
    float z = 0.f;
#pragma unroll
    for (int i = 0; i < HIDDEN; ++i) {
      const float y = sums[g * HIDDEN + i] / c;
      z += cosf(y) * Wout[i] + sinf(y) * Wout[HIDDEN + i];
    }
    z += bout[0];
    out[g] = 1.0f / (1.0f + expf(-z));
  }
}

// ---------------------------------------------------------------------------
extern "C" void kernel_launch(void* const* d_in, const int* in_sizes, int n_in,
                              void* d_out, int out_size, void* d_ws, size_t ws_size,
                              hipStream_t stream) {
  const float* x        = (const float*)d_in[0];
  const int*   eidx     = (const int*)d_in[1];
  const int*   batch    = (const int*)d_in[2];
  const float* W_in     = (const float*)d_in[3];
  const float* W_conv   = (const float*)d_in[4];
  const float* W_out    = (const float*)d_in[5];
  const float* b_out    = (const float*)d_in[6];
  float* out            = (float*)d_out;

  const int* src = eidx;            // edge_index[0]
  const int* dst = eidx + N_EDGES;  // edge_index[1]

  float* ws = (float*)d_ws;
  float* H       = ws;                         // 1.6M floats
  float* T       = ws + 1600000;               // 1.6M floats
  int*   row_ptr = (int*)(ws + 3200000);       // 50001 (pad 50008)
  int*   deg     = row_ptr + 50008;            // 50000 (pad 50048)
  int*   cursor  = deg + 50048;                // 50000 (pad 50048)
  int*   bsum    = cursor + 50048;             // 256
  int*   adj     = bsum + 256;                 // 800000
  float* SUMS    = (float*)(adj + 800000);     // 4096
  float* CNT     = SUMS + 4096;                // 128

  const int kan_blocks  = (N_NODES + 63) / 64;       // 782
  const int edge_blocks = (N_EDGES + 255) / 256;     // 3125
  const int gath_blocks = (N_NODES * 8 + 255) / 256; // 1563

  const int WCONV_STRIDE = 2 * HIDDEN * HIDDEN * GRID_SZ;  // 8192

  // --- CSR build (multi-block scan; every kernel chip-wide)
  zero_int_kernel<<<SCAN_BLOCKS, 256, 0, stream>>>(deg, N_NODES);
  hist_kernel<<<edge_blocks, 256, 0, stream>>>(dst, deg);
  scanA_kernel<<<SCAN_BLOCKS, 256, 0, stream>>>(deg, bsum);
  scanB_kernel<<<1, 256, 0, stream>>>(bsum, row_ptr);
  scanC_kernel<<<SCAN_BLOCKS, 256, 0, stream>>>(deg, bsum, row_ptr, cursor);
  fill_kernel<<<edge_blocks, 256, 0, stream>>>(src, dst, cursor, adj);

  // --- input KAN projection: H = KAN_in(x)
  kan_input_v8<<<kan_blocks, 256, 0, stream>>>(x, W_in, H);

  // --- layer 0: T = KAN_0(H); H = leaky(H + gather(T))
  kan_node_v8<<<kan_blocks, 256, 0, stream>>>(H, W_conv, T);
  gather_update_v2<<<gath_blocks, 256, 0, stream>>>(T, row_ptr, adj, H);

  // --- layer 1
  kan_node_v8<<<kan_blocks, 256, 0, stream>>>(H, W_conv + WCONV_STRIDE, T);
  gather_update_v2<<<gath_blocks, 256, 0, stream>>>(T, row_ptr, adj, H);

  // --- pool + readout
  zero_kernel<<<17, 256, 0, stream>>>(SUMS, N_GRAPHS * HIDDEN + N_GRAPHS);
  pool_rl<<<POOL_RANGES / 8, 256, 0, stream>>>(H, batch, SUMS, CNT);
  readout_kernel<<<1, 128, 0, stream>>>(SUMS, CNT, W_out, b_out, out);
}

// Round 12
// 308.301 us; speedup vs baseline: 6.5278x; 6.5278x over previous
//
#include <hip/hip_runtime.h>
#include <math.h>

#define N_NODES   50000
#define N_EDGES   800000
#define IN_FEAT   64
#define HIDDEN    32
#define GRID_SZ   4
#define N_GRAPHS  128
#define NEG_SLOPE 0.01f
#define SCAN_BLOCKS 196   // ceil(50000/256)

// ---------------------------------------------------------------------------
__global__ __launch_bounds__(256) void zero_int_kernel(int* __restrict__ p, int n) {
  const int i = blockIdx.x * 256 + threadIdx.x;
  if (i < n) p[i] = 0;
}
__global__ __launch_bounds__(256) void zero_kernel(float* __restrict__ p, int n) {
  const int i = blockIdx.x * 256 + threadIdx.x;
  if (i < n) p[i] = 0.f;
}

// ---------------------------------------------------------------------------
// CSR build: histogram of dst into deg[]
// ---------------------------------------------------------------------------
__global__ __launch_bounds__(256) void hist_kernel(
    const int* __restrict__ dst, int* __restrict__ deg) {
  const int e = blockIdx.x * 256 + threadIdx.x;
  if (e < N_EDGES) atomicAdd(&deg[dst[e]], 1);
}

// multi-block scan, step A: per-block sums of deg -> bsum[SCAN_BLOCKS]
__global__ __launch_bounds__(256) void scanA_kernel(
    const int* __restrict__ deg, int* __restrict__ bsum) {
  const int i = blockIdx.x * 256 + threadIdx.x;
  int v = (i < N_NODES) ? deg[i] : 0;
#pragma unroll
  for (int o = 32; o > 0; o >>= 1) v += __shfl_down(v, o, 64);
  __shared__ int ws[4];
  if ((threadIdx.x & 63) == 0) ws[threadIdx.x >> 6] = v;
  __syncthreads();
  if (threadIdx.x == 0) bsum[blockIdx.x] = ws[0] + ws[1] + ws[2] + ws[3];
}

// step B: single small block scans the 196 block sums -> exclusive offsets
__global__ __launch_bounds__(256) void scanB_kernel(
    int* __restrict__ bsum, int* __restrict__ row_ptr) {
  __shared__ int sh[256];
  const int t = threadIdx.x;
  int v = (t < SCAN_BLOCKS) ? bsum[t] : 0;
  sh[t] = v;
  __syncthreads();
  for (int o = 1; o < 256; o <<= 1) {
    const int u = (t >= o) ? sh[t - o] : 0;
    __syncthreads();
    sh[t] += u;
    __syncthreads();
  }
  bsum[t] = (t == 0) ? 0 : sh[t - 1];   // exclusive
  if (t == 0) row_ptr[N_NODES] = N_EDGES;
}

// step C: per-block exclusive scan + block offset -> row_ptr, cursor
__global__ __launch_bounds__(256) void scanC_kernel(
    const int* __restrict__ deg, const int* __restrict__ bsum,
    int* __restrict__ row_ptr, int* __restrict__ cursor) {
  __shared__ int sh[256];
  const int t = threadIdx.x;
  const int i = blockIdx.x * 256 + t;
  const int v = (i < N_NODES) ? deg[i] : 0;
  sh[t] = v;
  __syncthreads();
  for (int o = 1; o < 256; o <<= 1) {
    const int u = (t >= o) ? sh[t - o] : 0;
    __syncthreads();
    sh[t] += u;
    __syncthreads();
  }
  if (i < N_NODES) {
    const int excl = bsum[blockIdx.x] + sh[t] - v;
    row_ptr[i] = excl;
    cursor[i] = excl;
  }
}

// fill: adj[pos] = src, pos = cursor[dst]++
__global__ __launch_bounds__(256) void fill_kernel(
    const int* __restrict__ src, const int* __restrict__ dst,
    int* __restrict__ cursor, int* __restrict__ adj) {
  const int e = blockIdx.x * 256 + threadIdx.x;
  if (e < N_EDGES) {
    const int pos = atomicAdd(&cursor[dst[e]], 1);
    adj[pos] = src[e];
  }
}

// ---------------------------------------------------------------------------
// gather + fused update, float4: 8 lanes/node, each lane owns 4 feats.
// H[n] = leaky(H[n] + sum_{k in row(n)} T[adj[k]])
// ---------------------------------------------------------------------------
__global__ __launch_bounds__(256) void gather_update_v2(
    const float* __restrict__ T, const int* __restrict__ row_ptr,
    const int* __restrict__ adj, float* __restrict__ H) {
  const int gid = blockIdx.x * 256 + threadIdx.x;
  const int n = gid >> 3;
  const int q = gid & 7;          // float4 slot within the 32-float row
  if (n >= N_NODES) return;
  const int lo = row_ptr[n], hi = row_ptr[n + 1];
  const float4* __restrict__ T4 = reinterpret_cast<const float4*>(T);
  float4 acc = make_float4(0.f, 0.f, 0.f, 0.f);
  for (int k = lo; k < hi; ++k) {
    const int s = adj[k];
    const float4 t = T4[s * 8 + q];
    acc.x += t.x; acc.y += t.y; acc.z += t.z; acc.w += t.w;
  }
  float4* __restrict__ H4 = reinterpret_cast<float4*>(H);
  float4 h = H4[n * 8 + q];
  h.x += acc.x; h.y += acc.y; h.z += acc.z; h.w += acc.w;
  h.x = (h.x >= 0.f) ? h.x : NEG_SLOPE * h.x;
  h.y = (h.y >= 0.f) ? h.y : NEG_SLOPE * h.y;
  h.z = (h.z >= 0.f) ? h.z : NEG_SLOPE * h.z;
  h.w = (h.w >= 0.f) ? h.w : NEG_SLOPE * h.w;
  H4[n * 8 + q] = h;
}

// ---------------------------------------------------------------------------
// Input KAN v9: 256 thr, 128 nodes/block; thread = (o-quad oq, 4-node group).
// 16 accumulators amortize weight reads: per i-step 8 w-b128 + 2 trig-b128
// for 128 FMA (vs v6's 9 ds / 64 FMA) -> ds-instr halved; LDS 73.9KB.
// Weights XOR-swizzled by oq (8 distinct bank-quads per read instr).
// Trig (c1,s1) only, rows padded to 260 floats, i chunked 8 at a time.
// ---------------------------------------------------------------------------
__global__ __launch_bounds__(256, 2) void kan_input_v9(
    const float* __restrict__ X, const float* __restrict__ W,
    float* __restrict__ H) {
  extern __shared__ float smem[];
  float4* __restrict__ w4 = reinterpret_cast<float4*>(smem);   // 4096 f4
  float* __restrict__ tg = smem + 16384;                       // 8*260 floats
  const int tid = threadIdx.x;
  const int n0 = blockIdx.x * 128;

  // stage weights, swizzled: slot-in-row = i ^ ((o>>2)&7)
  const float4* __restrict__ Wg = reinterpret_cast<const float4*>(W);
#pragma unroll
  for (int r = 0; r < 16; ++r) {
    const int idx = r * 256 + tid;       // 0..4095 (cos: 0..2047, sin: 2048+)
    const int part = idx >> 11;
    const int rem = idx & 2047;
    const int o = rem >> 6;
    const int i = rem & 63;
    w4[part * 2048 + o * 64 + (i ^ ((o >> 2) & 7))] = Wg[idx];
  }

  const int oq = tid & 7;        // outputs 4*oq .. 4*oq+3
  const int grp = tid >> 3;      // 0..31 -> local nodes 4*grp .. 4*grp+3
  const int nb = 4 * grp;

  float acc[4][4];
#pragma unroll
  for (int n = 0; n < 4; ++n)
#pragma unroll
    for (int q = 0; q < 4; ++q) acc[n][q] = 0.f;

  for (int ch = 0; ch < 8; ++ch) {
    __syncthreads();   // protect tg (prev chunk readers) + first-iter staging
    // phase 1: (c1,s1) for 128 nodes x 8 i
#pragma unroll
    for (int p = 0; p < 4; ++p) {
      const int lin = p * 256 + tid;
      const int il = lin & 7;
      const int node = lin >> 3;     // 0..127
      const int gn = n0 + node;
      const int gs = (gn < N_NODES) ? gn : (N_NODES - 1);
      const float v = X[gs * IN_FEAT + ch * 8 + il];
      float s1, c1;
      sincosf(v, &s1, &c1);
      *reinterpret_cast<float2*>(&tg[il * 260 + node * 2]) = make_float2(c1, s1);
    }
    __syncthreads();
    // phase 2
#pragma unroll
    for (int il = 0; il < 8; ++il) {
      const int i = ch * 8 + il;
      const float4 tA = *reinterpret_cast<const float4*>(&tg[il * 260 + nb * 2]);
      const float4 tB = *reinterpret_cast<const float4*>(&tg[il * 260 + nb * 2 + 4]);
      const float bc[4] = {tA.x, tA.z, tB.x, tB.z};
      const float bs[4] = {tA.y, tA.w, tB.y, tB.w};
      float cN[4][4], sN[4][4];
#pragma unroll
      for (int n = 0; n < 4; ++n) {
        const float c1 = bc[n], s1 = bs[n];
        const float c2 = c1*c1 - s1*s1, s2 = s1*c1 + c1*s1;
        const float c3 = c2*c1 - s2*s1, s3 = s2*c1 + c2*s1;
        const float c4 = c3*c1 - s3*s1, s4 = s3*c1 + c3*s1;
        cN[n][0]=c1; cN[n][1]=c2; cN[n][2]=c3; cN[n][3]=c4;
        sN[n][0]=s1; sN[n][1]=s2; sN[n][2]=s3; sN[n][3]=s4;
      }
      const int sl = i ^ oq;
#pragma unroll
      for (int q = 0; q < 4; ++q) {
        const float4 a = w4[(4 * oq + q) * 64 + sl];
        const float4 b = w4[2048 + (4 * oq + q) * 64 + sl];
#pragma unroll
        for (int n = 0; n < 4; ++n)
          acc[n][q] += cN[n][0]*a.x + cN[n][1]*a.y + cN[n][2]*a.z + cN[n][3]*a.w
                     + sN[n][0]*b.x + sN[n][1]*b.y + sN[n][2]*b.z + sN[n][3]*b.w;
      }
    }
  }
#pragma unroll
  for (int n = 0; n < 4; ++n) {
    const int gn = n0 + nb + n;
    if (gn < N_NODES)
      *reinterpret_cast<float4*>(&H[gn * HIDDEN + 4 * oq]) =
          make_float4(acc[n][0], acc[n][1], acc[n][2], acc[n][3]);
  }
}

// ---------------------------------------------------------------------------
// Conv KAN v9: same structure; 32 i un-chunked. LDS 64.5KB -> 2 blocks/CU.
// ---------------------------------------------------------------------------
__global__ __launch_bounds__(256, 2) void kan_node_v9(
    const float* __restrict__ Hin, const float* __restrict__ W,
    float* __restrict__ T) {
  extern __shared__ float smem[];
  float4* __restrict__ w4 = reinterpret_cast<float4*>(smem);   // 2048 f4
  float* __restrict__ tg = smem + 8192;                        // 32*260 floats
  const int tid = threadIdx.x;
  const int n0 = blockIdx.x * 128;

  const float4* __restrict__ Wg = reinterpret_cast<const float4*>(W);
#pragma unroll
  for (int r = 0; r < 8; ++r) {
    const int idx = r * 256 + tid;       // 0..2047
    const int part = idx >> 10;
    const int rem = idx & 1023;
    const int o = rem >> 5;
    const int i = rem & 31;
    w4[part * 1024 + o * 32 + (i ^ ((o >> 2) & 7))] = Wg[idx];
  }

  // phase 1: (c1,s1) for 128 nodes x 32 i
#pragma unroll
  for (int p = 0; p < 16; ++p) {
    const int lin = p * 256 + tid;
    const int il = lin & 31;
    const int node = lin >> 5;       // 0..127
    const int gn = n0 + node;
    const int gs = (gn < N_NODES) ? gn : (N_NODES - 1);
    const float v = Hin[gs * HIDDEN + il];
    float s1, c1;
    sincosf(v, &s1, &c1);
    *reinterpret_cast<float2*>(&tg[il * 260 + node * 2]) = make_float2(c1, s1);
  }
  __syncthreads();

  const int oq = tid & 7;
  const int grp = tid >> 3;
  const int nb = 4 * grp;

  float acc[4][4];
#pragma unroll
  for (int n = 0; n < 4; ++n)
#pragma unroll
    for (int q = 0; q < 4; ++q) acc[n][q] = 0.f;

#pragma unroll 4
  for (int i = 0; i < HIDDEN; ++i) {
    const float4 tA = *reinterpret_cast<const float4*>(&tg[i * 260 + nb * 2]);
    const float4 tB = *reinterpret_cast<const float4*>(&tg[i * 260 + nb * 2 + 4]);
    const float bc[4] = {tA.x, tA.z, tB.x, tB.z};
    const float bs[4] = {tA.y, tA.w, tB.y, tB.w};
    float cN[4][4], sN[4][4];
#pragma unroll
    for (int n = 0; n < 4; ++n) {
      const float c1 = bc[n], s1 = bs[n];
      const float c2 = c1*c1 - s1*s1, s2 = s1*c1 + c1*s1;
      const float c3 = c2*c1 - s2*s1, s3 = s2*c1 + c2*s1;
      const float c4 = c3*c1 - s3*s1, s4 = s3*c1 + c3*s1;
      cN[n][0]=c1; cN[n][1]=c2; cN[n][2]=c3; cN[n][3]=c4;
      sN[n][0]=s1; sN[n][1]=s2; sN[n][2]=s3; sN[n][3]=s4;
    }
    const int sl = i ^ oq;
#pragma unroll
    for (int q = 0; q < 4; ++q) {
      const float4 a = w4[(4 * oq + q) * 32 + sl];
      const float4 b = w4[1024 + (4 * oq + q) * 32 + sl];
#pragma unroll
      for (int n = 0; n < 4; ++n)
        acc[n][q] += cN[n][0]*a.x + cN[n][1]*a.y + cN[n][2]*a.z + cN[n][3]*a.w
                   + sN[n][0]*b.x + sN[n][1]*b.y + sN[n][2]*b.z + sN[n][3]*b.w;
    }
  }
#pragma unroll
  for (int n = 0; n < 4; ++n) {
    const int gn = n0 + nb + n;
    if (gn < N_NODES)
      *reinterpret_cast<float4*>(&T[gn * HIDDEN + 4 * oq]) =
          make_float4(acc[n][0], acc[n][1], acc[n][2], acc[n][3]);
  }
}

// ---------------------------------------------------------------------------
// pool via run-length over sorted batch: thread = (range r, feat f)
// ---------------------------------------------------------------------------
#define POOL_RANGES 512
__global__ __launch_bounds__(256) void pool_rl(
    const float* __restrict__ H, const int* __restrict__ batch,
    float* __restrict__ sums, float* __restrict__ cnt) {
  const int tid = threadIdx.x;
  const int f = tid & 31;
  const int r = blockIdx.x * 8 + (tid >> 5);
  const int PER = (N_NODES + POOL_RANGES - 1) / POOL_RANGES;  // 98
  int n = r * PER;
  const int end = (n + PER < N_NODES) ? n + PER : N_NODES;
  if (n >= end) return;
  int g = batch[n];
  float acc = 0.f, c = 0.f;
  for (; n < end; ++n) {
    const int gn = batch[n];
    if (gn != g) {
      atomicAdd(&sums[g * HIDDEN + f], acc);
      if (f == 0) atomicAdd(&cnt[g], c);
      g = gn; acc = 0.f; c = 0.f;
    }
    acc += H[n * HIDDEN + f];
    c += 1.f;
  }
  atomicAdd(&sums[g * HIDDEN + f], acc);
  if (f == 0) atomicAdd(&cnt[g], c);
}

// ---------------------------------------------------------------------------
__global__ __launch_bounds__(128) void readout_kernel(
    const float* __restrict__ sums, const float* __restrict__ cnt,
    const float* __restrict__ Wout, const float* __restrict__ bout,
    float* __restrict__ out) {
  const int g = threadIdx.x;
  if (g < N_GRAPHS) {
    const float c = fmaxf(cnt[g], 1.0f);
    float z = 0.f;
#pragma unroll
    for (int i = 0; i < HIDDEN; ++i) {
      const float y = sums[g * HIDDEN + i] / c;
      z += cosf(y) * Wout[i] + sinf(y) * Wout[HIDDEN + i];
    }
    z += bout[0];
    out[g] = 1.0f / (1.0f + expf(-z));
  }
}

// ---------------------------------------------------------------------------
extern "C" void kernel_launch(void* const* d_in, const int* in_sizes, int n_in,
                              void* d_out, int out_size, void* d_ws, size_t ws_size,
                              hipStream_t stream) {
  const float* x        = (const float*)d_in[0];
  const int*   eidx     = (const int*)d_in[1];
  const int*   batch    = (const int*)d_in[2];
  const float* W_in     = (const float*)d_in[3];
  const float* W_conv   = (const float*)d_in[4];
  const float* W_out    = (const float*)d_in[5];
  const float* b_out    = (const float*)d_in[6];
  float* out            = (float*)d_out;

  const int* src = eidx;            // edge_index[0]
  const int* dst = eidx + N_EDGES;  // edge_index[1]

  float* ws = (float*)d_ws;
  float* H       = ws;                         // 1.6M floats
  float* T       = ws + 1600000;               // 1.6M floats
  int*   row_ptr = (int*)(ws + 3200000);       // 50001 (pad 50008)
  int*   deg     = row_ptr + 50008;            // 50000 (pad 50048)
  int*   cursor  = deg + 50048;                // 50000 (pad 50048)
  int*   bsum    = cursor + 50048;             // 256
  int*   adj     = bsum + 256;                 // 800000
  float* SUMS    = (float*)(adj + 800000);     // 4096
  float* CNT     = SUMS + 4096;                // 128

  const int kan_blocks  = (N_NODES + 127) / 128;     // 391
  const int edge_blocks = (N_EDGES + 255) / 256;     // 3125
  const int gath_blocks = (N_NODES * 8 + 255) / 256; // 1563

  const size_t in_lds   = (size_t)(16384 + 8 * 260) * 4;   // 73856 B (2/CU)
  const size_t conv_lds = (size_t)(8192 + 32 * 260) * 4;   // 66048 B (2/CU)
  const int WCONV_STRIDE = 2 * HIDDEN * HIDDEN * GRID_SZ;  // 8192

  // --- CSR build (multi-block scan; every kernel chip-wide)
  zero_int_kernel<<<SCAN_BLOCKS, 256, 0, stream>>>(deg, N_NODES);
  hist_kernel<<<edge_blocks, 256, 0, stream>>>(dst, deg);
  scanA_kernel<<<SCAN_BLOCKS, 256, 0, stream>>>(deg, bsum);
  scanB_kernel<<<1, 256, 0, stream>>>(bsum, row_ptr);
  scanC_kernel<<<SCAN_BLOCKS, 256, 0, stream>>>(deg, bsum, row_ptr, cursor);
  fill_kernel<<<edge_blocks, 256, 0, stream>>>(src, dst, cursor, adj);

  // --- input KAN projection: H = KAN_in(x)
  kan_input_v9<<<kan_blocks, 256, in_lds, stream>>>(x, W_in, H);

  // --- layer 0: T = KAN_0(H); H = leaky(H + gather(T))
  kan_node_v9<<<kan_blocks, 256, conv_lds, stream>>>(H, W_conv, T);
  gather_update_v2<<<gath_blocks, 256, 0, stream>>>(T, row_ptr, adj, H);

  // --- layer 1
  kan_node_v9<<<kan_blocks, 256, conv_lds, stream>>>(H, W_conv + WCONV_STRIDE, T);
  gather_update_v2<<<gath_blocks, 256, 0, stream>>>(T, row_ptr, adj, H);

  // --- pool + readout
  zero_kernel<<<17, 256, 0, stream>>>(SUMS, N_GRAPHS * HIDDEN + N_GRAPHS);
  pool_rl<<<POOL_RANGES / 8, 256, 0, stream>>>(H, batch, SUMS, CNT);
  readout_kernel<<<1, 128, 0, stream>>>(SUMS, CNT, W_out, b_out, out);
}